// Round 2
// baseline (393.934 us; speedup 1.0000x reference)
//
#include <hip/hip_runtime.h>

// GAT attention scores, R10: 2D (row-range x col-tile) binning.
//
// R9 post-mortem: removing 1 of 2 divergent gathers in range_sum changed
// NOTHING (90.2 -> 91.0us). The removed gather was range-local (L1-hit);
// the surviving one is random over 800KB (L1-miss). => wall = L1-miss
// count x latency under a per-CU MSHR cap, not divergent-instr count.
// Fix: make ALL per-edge reads local. Sort edges by (row>>8, col>>11);
// per block, stage s1/ln row-tile (4KB) + s2 col-tile (32KB) in LDS; the
// s2 table is then read as coalesced L2 streams (157MB @ ~34TB/s ~ 5us)
// instead of 1.6M random line misses. Final pass computes alpha from LDS
// and scatter-STORES to out (stores are fire-and-forget; R9 proved
// scattered stores cheap). eid rides through the sort in uint2 binned.
//
// ws (14.6MB < 15.86MB proven-safe): s2h .8M | combh 1.6M | binned2 12.84M
//   | tstart/tend/gtot 59K
// out-region scratch (consumed before edge_out rewrites all of out):
//   partial 6.4M | counts 2.5M | bbase 2.5M

constexpr int NN = 50000;
constexpr int NE = 1600000;
constexpr int F  = 32;
constexpr int H  = 8;
constexpr float ALPHA = 0.2f;
constexpr float EPS   = 1e-12f;

constexpr int RSH     = 8;
constexpr int RNODES  = 1 << RSH;                   // 256 nodes/row-range
constexpr int NR      = (NN + RNODES - 1) / RNODES; // 196
constexpr int CSH     = 11;
constexpr int CNODES  = 1 << CSH;                   // 2048 nodes/col-tile (32KB fp16)
constexpr int NCX     = (NN + CNODES - 1) / CNODES; // 25
constexpr int NBIN    = NR * NCX;                   // 4900
constexpr int NB2     = 128;                        // blocks in bin passes
constexpr int CHUNK2  = NE / NB2;                   // 12500 (divisible by 4)
constexpr int SC      = 4;                          // col-tile stripes

typedef _Float16 v8h __attribute__((ext_vector_type(8)));

__global__ __launch_bounds__(256) void node_proj_kernel(
    const float* __restrict__ x, const float* __restrict__ aa,
    float* __restrict__ combh, float* __restrict__ s2h)
{
    __shared__ float aal[H * 2 * F];
    for (int i = threadIdx.x; i < H * 2 * F; i += 256) aal[i] = aa[i];
    __syncthreads();

    int n = blockIdx.x * 256 + threadIdx.x;
    if (n >= NN) return;

    const float4* xp = reinterpret_cast<const float4*>(x + (size_t)n * F);
    float4 xv[F / 4];
#pragma unroll
    for (int i = 0; i < F / 4; ++i) xv[i] = xp[i];

    float o1[H], o2[H];
#pragma unroll
    for (int h = 0; h < H; ++h) {
        const float* a1 = &aal[h * 2 * F];
        const float* a2 = a1 + F;
        float acc1 = 0.f, acc2 = 0.f;
#pragma unroll
        for (int i = 0; i < F / 4; ++i) {
            acc1 = fmaf(a1[4*i+0], xv[i].x, acc1);
            acc1 = fmaf(a1[4*i+1], xv[i].y, acc1);
            acc1 = fmaf(a1[4*i+2], xv[i].z, acc1);
            acc1 = fmaf(a1[4*i+3], xv[i].w, acc1);
            acc2 = fmaf(a2[4*i+0], xv[i].x, acc2);
            acc2 = fmaf(a2[4*i+1], xv[i].y, acc2);
            acc2 = fmaf(a2[4*i+2], xv[i].z, acc2);
            acc2 = fmaf(a2[4*i+3], xv[i].w, acc2);
        }
        o1[h] = acc1; o2[h] = acc2;
    }

    v8h s1v, s2v;
#pragma unroll
    for (int h = 0; h < H; ++h) { s1v[h] = (_Float16)o1[h]; s2v[h] = (_Float16)o2[h]; }
    reinterpret_cast<v8h*>(combh)[(size_t)n * 2] = s1v;   // lnrech slot filled later
    reinterpret_cast<v8h*>(s2h)[n] = s2v;
}

// counts layout: counts[blk * NBIN + bin]  (rows contiguous per block)
__global__ __launch_bounds__(256) void bin_count_kernel(
    const int* __restrict__ row, const int* __restrict__ col,
    int* __restrict__ counts)
{
    __shared__ int cnt[NBIN];
    for (int i = threadIdx.x; i < NBIN; i += 256) cnt[i] = 0;
    __syncthreads();
    const int base = blockIdx.x * CHUNK2;
    const int4* r4 = reinterpret_cast<const int4*>(row + base);
    const int4* c4 = reinterpret_cast<const int4*>(col + base);
    for (int i = threadIdx.x; i < CHUNK2 / 4; i += 256) {
        int4 r = r4[i], c = c4[i];
        atomicAdd(&cnt[(r.x >> RSH) * NCX + (c.x >> CSH)], 1);
        atomicAdd(&cnt[(r.y >> RSH) * NCX + (c.y >> CSH)], 1);
        atomicAdd(&cnt[(r.z >> RSH) * NCX + (c.z >> CSH)], 1);
        atomicAdd(&cnt[(r.w >> RSH) * NCX + (c.w >> CSH)], 1);
    }
    __syncthreads();
    int* myrow = counts + (size_t)blockIdx.x * NBIN;
    for (int i = threadIdx.x; i < NBIN; i += 256) myrow[i] = cnt[i];
}

// per-bin totals (parallel over bins; coalesced strided reads)
__global__ __launch_bounds__(256) void scan_a_kernel(
    const int* __restrict__ counts, int* __restrict__ gtot)
{
    int b = blockIdx.x * 256 + threadIdx.x;
    if (b >= NBIN) return;
    int s = 0;
    for (int k = 0; k < NB2; ++k) s += counts[(size_t)k * NBIN + b];
    gtot[b] = s;
}

// single block: exclusive scan of 2-aligned bin sizes -> tstart/tend
__global__ __launch_bounds__(1024) void scan_b_kernel(
    const int* __restrict__ gtot, int* __restrict__ tstart, int* __restrict__ tend)
{
    __shared__ int tot[NBIN];
    __shared__ int tp[1024];
    const int t = threadIdx.x;
    for (int b = t; b < NBIN; b += 1024) tot[b] = gtot[b];
    __syncthreads();
    constexpr int PB = (NBIN + 1023) / 1024;   // 5
    int s = 0;
#pragma unroll
    for (int j = 0; j < PB; ++j) {
        int b = t * PB + j;
        if (b < NBIN) s += (tot[b] + 1) & ~1;  // pad each bin to 2 edges
    }
    tp[t] = s;
    __syncthreads();
    for (int off = 1; off < 1024; off <<= 1) {
        int v = (t >= off) ? tp[t - off] : 0;
        __syncthreads();
        tp[t] += v;
        __syncthreads();
    }
    int run = tp[t] - s;                       // exclusive prefix
#pragma unroll
    for (int j = 0; j < PB; ++j) {
        int b = t * PB + j;
        if (b < NBIN) {
            tstart[b] = run;
            tend[b] = run + tot[b];
            run += (tot[b] + 1) & ~1;
        }
    }
    if (t == 1023) tstart[NBIN] = tp[1023];
}

// per-(block,bin) bases: bbase[k*NBIN+b] = tstart[b] + prefix over blocks
__global__ __launch_bounds__(256) void scan_c_kernel(
    const int* __restrict__ counts, const int* __restrict__ tstart,
    int* __restrict__ bbase)
{
    int b = blockIdx.x * 256 + threadIdx.x;
    if (b >= NBIN) return;
    int run = tstart[b];
    for (int k = 0; k < NB2; ++k) {
        bbase[(size_t)k * NBIN + b] = run;
        run += counts[(size_t)k * NBIN + b];
    }
}

__global__ __launch_bounds__(256) void bin_scatter_kernel(
    const int* __restrict__ row, const int* __restrict__ col,
    const int* __restrict__ bbase, const int* __restrict__ tstart,
    const int* __restrict__ tend, uint2* __restrict__ binned)
{
    // block 0 fills alignment pads with sentinels (ws is 0xAA-poisoned!)
    if (blockIdx.x == 0) {
        for (int b = threadIdx.x; b < NBIN; b += 256) {
            for (int p = tend[b]; p < tstart[b + 1]; ++p)
                binned[p] = make_uint2(0xFFFFFFFFu, 0u);
        }
    }
    __shared__ int cur[NBIN];
    const int* myb = bbase + (size_t)blockIdx.x * NBIN;
    for (int i = threadIdx.x; i < NBIN; i += 256) cur[i] = myb[i];
    __syncthreads();
    const int base = blockIdx.x * CHUNK2;
    const int4* r4 = reinterpret_cast<const int4*>(row + base);
    const int4* c4 = reinterpret_cast<const int4*>(col + base);
    for (int i = threadIdx.x; i < CHUNK2 / 4; i += 256) {
        int4 r = r4[i], c = c4[i];
        int rr[4] = {r.x, r.y, r.z, r.w};
        int cc[4] = {c.x, c.y, c.z, c.w};
#pragma unroll
        for (int k = 0; k < 4; ++k) {
            int bin = (rr[k] >> RSH) * NCX + (cc[k] >> CSH);
            int pos = atomicAdd(&cur[bin], 1);
            binned[pos] = make_uint2(((unsigned)rr[k] << 16) | (unsigned)cc[k],
                                     (unsigned)(base + i * 4 + k));
        }
    }
}

// grid (NR, SC), 512 thr: all per-edge reads from LDS; s2 streamed by tile.
__global__ __launch_bounds__(512) void range_sum_kernel(
    const uint2* __restrict__ binned, const int* __restrict__ tstart,
    const float* __restrict__ combh, const float* __restrict__ s2h,
    float* __restrict__ partial)
{
    __shared__ float acc[RNODES * H];   // 8 KB (swizzled)
    __shared__ v8h  sh1[RNODES];        // 4 KB
    __shared__ v8h  s2t[CNODES];        // 32 KB
    const int rx = blockIdx.x;
    const int rbase = rx << RSH;
    const v8h* combv = reinterpret_cast<const v8h*>(combh);
    const v8h* s2v   = reinterpret_cast<const v8h*>(s2h);

    for (int i = threadIdx.x; i < RNODES * H; i += 512) acc[i] = 0.f;
    for (int d = threadIdx.x; d < RNODES; d += 512) {
        int n = rbase + d;
        if (n >= NN) n = NN - 1;
        sh1[d] = combv[(size_t)n * 2];
    }

    const uint4* b4 = reinterpret_cast<const uint4*>(binned);
    for (int cx = blockIdx.y; cx < NCX; cx += SC) {
        __syncthreads();                       // protect s2t from prev readers
        const int cb = cx << CSH;
        for (int j = threadIdx.x; j < CNODES; j += 512) {
            int n = cb + j;
            if (n >= NN) n = NN - 1;
            s2t[j] = s2v[n];
        }
        __syncthreads();
        const int bin = rx * NCX + cx;
        const int p0 = tstart[bin] >> 1, p1 = tstart[bin + 1] >> 1;
        for (int i = p0 + threadIdx.x; i < p1; i += 512) {
            uint4 q = b4[i];
            unsigned pk[2] = {q.x, q.z};
#pragma unroll
            for (int k = 0; k < 2; ++k) {
                unsigned d = (pk[k] >> 16) - (unsigned)rbase;
                if (d >= (unsigned)RNODES) continue;     // sentinel pad
                unsigned cl = (pk[k] & 0xFFFFu) - (unsigned)cb;
                v8h a = sh1[d];
                v8h b = s2t[cl];
                float* ap = &acc[d << 3];
#pragma unroll
                for (int h = 0; h < H; ++h) {
                    float t = (float)a[h] + (float)b[h];
                    t = fmaxf(t, ALPHA * t);
                    atomicAdd(ap + ((h + d) & 7), __expf(t));   // swizzled banks
                }
            }
        }
    }
    __syncthreads();

    const int cnt = min(RNODES, NN - rbase);
    float* outp = partial + ((size_t)blockIdx.y * NN + rbase) * H;
    for (int j = threadIdx.x; j < cnt * H; j += 512) {
        int d = j >> 3, h = j & 7;
        outp[j] = acc[(d << 3) + ((h + d) & 7)];       // unswizzle
    }
}

// per-node: fold stripe partials, store lnrec = -log(sum+eps) as fp16
__global__ __launch_bounds__(256) void node_final_kernel(
    const float* __restrict__ partial, float* __restrict__ combh)
{
    int n = blockIdx.x * 256 + threadIdx.x;
    if (n >= NN) return;
    const float4* p4 = reinterpret_cast<const float4*>(partial);
    float4 lo = p4[(size_t)n * 2], hi = p4[(size_t)n * 2 + 1];
#pragma unroll
    for (int s = 1; s < SC; ++s) {
        float4 a = p4[(size_t)s * (NN * 2) + n * 2];
        float4 b = p4[(size_t)s * (NN * 2) + n * 2 + 1];
        lo.x += a.x; lo.y += a.y; lo.z += a.z; lo.w += a.w;
        hi.x += b.x; hi.y += b.y; hi.z += b.z; hi.w += b.w;
    }
    float s8[8] = {lo.x, lo.y, lo.z, lo.w, hi.x, hi.y, hi.z, hi.w};
    v8h lnh;
#pragma unroll
    for (int h = 0; h < H; ++h) lnh[h] = (_Float16)(-__logf(s8[h] + EPS));
    reinterpret_cast<v8h*>(combh)[(size_t)n * 2 + 1] = lnh;
}

// grid (NR, SC): alpha from LDS tiles; scatter-store to out[h][eid].
// Every edge appears exactly once in binned => full out coverage.
__global__ __launch_bounds__(512) void edge_out_kernel(
    const uint2* __restrict__ binned, const int* __restrict__ tstart,
    const float* __restrict__ combh, const float* __restrict__ s2h,
    float* __restrict__ out)
{
    __shared__ v8h sh1[RNODES];    // 4 KB
    __shared__ v8h shln[RNODES];   // 4 KB
    __shared__ v8h s2t[CNODES];    // 32 KB
    const int rx = blockIdx.x;
    const int rbase = rx << RSH;
    const v8h* combv = reinterpret_cast<const v8h*>(combh);
    const v8h* s2v   = reinterpret_cast<const v8h*>(s2h);

    for (int d = threadIdx.x; d < RNODES; d += 512) {
        int n = rbase + d;
        if (n >= NN) n = NN - 1;
        sh1[d]  = combv[(size_t)n * 2];
        shln[d] = combv[(size_t)n * 2 + 1];
    }

    const uint4* b4 = reinterpret_cast<const uint4*>(binned);
    for (int cx = blockIdx.y; cx < NCX; cx += SC) {
        __syncthreads();
        const int cb = cx << CSH;
        for (int j = threadIdx.x; j < CNODES; j += 512) {
            int n = cb + j;
            if (n >= NN) n = NN - 1;
            s2t[j] = s2v[n];
        }
        __syncthreads();
        const int bin = rx * NCX + cx;
        const int p0 = tstart[bin] >> 1, p1 = tstart[bin + 1] >> 1;
        for (int i = p0 + threadIdx.x; i < p1; i += 512) {
            uint4 q = b4[i];
            unsigned pk[2] = {q.x, q.z};
            unsigned ei[2] = {q.y, q.w};
#pragma unroll
            for (int k = 0; k < 2; ++k) {
                unsigned d = (pk[k] >> 16) - (unsigned)rbase;
                if (d >= (unsigned)RNODES) continue;     // sentinel pad
                unsigned cl = (pk[k] & 0xFFFFu) - (unsigned)cb;
                v8h a = sh1[d], ln = shln[d], b = s2t[cl];
                size_t eid = ei[k];
#pragma unroll
                for (int h = 0; h < H; ++h) {
                    float t = (float)a[h] + (float)b[h];
                    t = fmaxf(t, ALPHA * t);
                    out[(size_t)h * NE + eid] = __expf(t + (float)ln[h]);
                }
            }
        }
    }
}

extern "C" void kernel_launch(void* const* d_in, const int* in_sizes, int n_in,
                              void* d_out, int out_size, void* d_ws, size_t ws_size,
                              hipStream_t stream) {
    const float* x   = (const float*)d_in[0];
    const float* aa  = (const float*)d_in[1];
    const int*   row = (const int*)d_in[2];
    const int*   col = (const int*)d_in[3];
    float* out = (float*)d_out;

    // ws (14.6 MB)
    float* s2h   = (float*)d_ws;                          // NN*4 floats
    float* combh = s2h + (size_t)NN * 4;                  // NN*8 floats
    uint2* binned = (uint2*)(combh + (size_t)NN * 8);     // NE + NBIN + 64
    int* tstart  = (int*)(binned + NE + NBIN + 64);       // NBIN+1
    int* tend    = tstart + NBIN + 1;                     // NBIN
    int* gtot    = tend + NBIN;                           // NBIN

    // out-region scratch (fully consumed before edge_out rewrites out)
    float* partial = out;                                 // SC*NN*H floats (6.4M)
    int* counts = (int*)(out + (size_t)SC * NN * H);      // NB2*NBIN (2.5M)
    int* bbase  = counts + (size_t)NB2 * NBIN;            // NB2*NBIN (2.5M)

    node_proj_kernel<<<(NN + 255) / 256, 256, 0, stream>>>(x, aa, combh, s2h);
    bin_count_kernel<<<NB2, 256, 0, stream>>>(row, col, counts);
    scan_a_kernel<<<(NBIN + 255) / 256, 256, 0, stream>>>(counts, gtot);
    scan_b_kernel<<<1, 1024, 0, stream>>>(gtot, tstart, tend);
    scan_c_kernel<<<(NBIN + 255) / 256, 256, 0, stream>>>(counts, tstart, bbase);
    bin_scatter_kernel<<<NB2, 256, 0, stream>>>(row, col, bbase, tstart, tend, binned);
    range_sum_kernel<<<dim3(NR, SC), 512, 0, stream>>>(binned, tstart, combh, s2h, partial);
    node_final_kernel<<<(NN + 255) / 256, 256, 0, stream>>>(partial, combh);
    edge_out_kernel<<<dim3(NR, SC), 512, 0, stream>>>(binned, tstart, combh, s2h, out);
}

// Round 3
// 260.043 us; speedup vs baseline: 1.5149x; 1.5149x over previous
//
#include <hip/hip_runtime.h>

// GAT attention scores, R11: composite of measured-best passes.
//
// R10 post-mortem: edge_out's 8 scattered 4-B stores/edge cost 32 B HBM
// traffic each (WRITE_SIZE 408 MB vs 51 ideal) -> 170us. Reads from LDS
// tiles were free (VALUBusy 4%, FETCH 18MB). range_sum left the top-5
// (was pinned at 90us in R8/R9) -> eliminating the s2 miss stream worked.
// Cost classes (measured): coalesced streams cheap; LDS/exp free; random
// 1.6M-deep miss streams ~45-90us each; scattered 4B stores 32B each.
//
// R11: keep 2D-tiled range_sum (all reads LDS); revert edge_out to
// eid-order gather (2 miss streams, coalesced float4 stores/plane);
// binned entries back to 4 B (eid no longer carried) halving
// bin_scatter's scattered-store traffic.
//
// ws (~9.0MB): s2h .8M | combh 1.6M | binned 6.48M | tstart/tend/gtot 59K
// out-region scratch (consumed before edge_out rewrites all of out):
//   partial 6.4M | counts 2.5M | bbase 2.5M

constexpr int NN = 50000;
constexpr int NE = 1600000;
constexpr int F  = 32;
constexpr int H  = 8;
constexpr float ALPHA = 0.2f;
constexpr float EPS   = 1e-12f;

constexpr int RSH     = 8;
constexpr int RNODES  = 1 << RSH;                   // 256 nodes/row-range
constexpr int NR      = (NN + RNODES - 1) / RNODES; // 196
constexpr int CSH     = 11;
constexpr int CNODES  = 1 << CSH;                   // 2048 nodes/col-tile (32KB fp16)
constexpr int NCX     = (NN + CNODES - 1) / CNODES; // 25
constexpr int NBIN    = NR * NCX;                   // 4900
constexpr int NB2     = 128;                        // blocks in bin passes
constexpr int CHUNK2  = NE / NB2;                   // 12500
constexpr int SC      = 4;                          // col-tile stripes

typedef _Float16 v8h __attribute__((ext_vector_type(8)));

__global__ __launch_bounds__(256) void node_proj_kernel(
    const float* __restrict__ x, const float* __restrict__ aa,
    float* __restrict__ combh, float* __restrict__ s2h)
{
    __shared__ float aal[H * 2 * F];
    for (int i = threadIdx.x; i < H * 2 * F; i += 256) aal[i] = aa[i];
    __syncthreads();

    int n = blockIdx.x * 256 + threadIdx.x;
    if (n >= NN) return;

    const float4* xp = reinterpret_cast<const float4*>(x + (size_t)n * F);
    float4 xv[F / 4];
#pragma unroll
    for (int i = 0; i < F / 4; ++i) xv[i] = xp[i];

    float o1[H], o2[H];
#pragma unroll
    for (int h = 0; h < H; ++h) {
        const float* a1 = &aal[h * 2 * F];
        const float* a2 = a1 + F;
        float acc1 = 0.f, acc2 = 0.f;
#pragma unroll
        for (int i = 0; i < F / 4; ++i) {
            acc1 = fmaf(a1[4*i+0], xv[i].x, acc1);
            acc1 = fmaf(a1[4*i+1], xv[i].y, acc1);
            acc1 = fmaf(a1[4*i+2], xv[i].z, acc1);
            acc1 = fmaf(a1[4*i+3], xv[i].w, acc1);
            acc2 = fmaf(a2[4*i+0], xv[i].x, acc2);
            acc2 = fmaf(a2[4*i+1], xv[i].y, acc2);
            acc2 = fmaf(a2[4*i+2], xv[i].z, acc2);
            acc2 = fmaf(a2[4*i+3], xv[i].w, acc2);
        }
        o1[h] = acc1; o2[h] = acc2;
    }

    v8h s1v, s2v;
#pragma unroll
    for (int h = 0; h < H; ++h) { s1v[h] = (_Float16)o1[h]; s2v[h] = (_Float16)o2[h]; }
    reinterpret_cast<v8h*>(combh)[(size_t)n * 2] = s1v;   // lnrech slot filled later
    reinterpret_cast<v8h*>(s2h)[n] = s2v;
}

// counts layout: counts[blk * NBIN + bin]
__global__ __launch_bounds__(256) void bin_count_kernel(
    const int* __restrict__ row, const int* __restrict__ col,
    int* __restrict__ counts)
{
    __shared__ int cnt[NBIN];
    for (int i = threadIdx.x; i < NBIN; i += 256) cnt[i] = 0;
    __syncthreads();
    const int base = blockIdx.x * CHUNK2;
    const int4* r4 = reinterpret_cast<const int4*>(row + base);
    const int4* c4 = reinterpret_cast<const int4*>(col + base);
    for (int i = threadIdx.x; i < CHUNK2 / 4; i += 256) {
        int4 r = r4[i], c = c4[i];
        atomicAdd(&cnt[(r.x >> RSH) * NCX + (c.x >> CSH)], 1);
        atomicAdd(&cnt[(r.y >> RSH) * NCX + (c.y >> CSH)], 1);
        atomicAdd(&cnt[(r.z >> RSH) * NCX + (c.z >> CSH)], 1);
        atomicAdd(&cnt[(r.w >> RSH) * NCX + (c.w >> CSH)], 1);
    }
    __syncthreads();
    int* myrow = counts + (size_t)blockIdx.x * NBIN;
    for (int i = threadIdx.x; i < NBIN; i += 256) myrow[i] = cnt[i];
}

// per-bin totals
__global__ __launch_bounds__(256) void scan_a_kernel(
    const int* __restrict__ counts, int* __restrict__ gtot)
{
    int b = blockIdx.x * 256 + threadIdx.x;
    if (b >= NBIN) return;
    int s = 0;
    for (int k = 0; k < NB2; ++k) s += counts[(size_t)k * NBIN + b];
    gtot[b] = s;
}

// single block: exclusive scan of 4-aligned bin sizes -> tstart/tend
__global__ __launch_bounds__(1024) void scan_b_kernel(
    const int* __restrict__ gtot, int* __restrict__ tstart, int* __restrict__ tend)
{
    __shared__ int tot[NBIN];
    __shared__ int tp[1024];
    const int t = threadIdx.x;
    for (int b = t; b < NBIN; b += 1024) tot[b] = gtot[b];
    __syncthreads();
    constexpr int PB = (NBIN + 1023) / 1024;   // 5
    int s = 0;
#pragma unroll
    for (int j = 0; j < PB; ++j) {
        int b = t * PB + j;
        if (b < NBIN) s += (tot[b] + 3) & ~3;  // pad each bin to 4 entries (16B)
    }
    tp[t] = s;
    __syncthreads();
    for (int off = 1; off < 1024; off <<= 1) {
        int v = (t >= off) ? tp[t - off] : 0;
        __syncthreads();
        tp[t] += v;
        __syncthreads();
    }
    int run = tp[t] - s;                       // exclusive prefix
#pragma unroll
    for (int j = 0; j < PB; ++j) {
        int b = t * PB + j;
        if (b < NBIN) {
            tstart[b] = run;
            tend[b] = run + tot[b];
            run += (tot[b] + 3) & ~3;
        }
    }
    if (t == 1023) tstart[NBIN] = tp[1023];
}

// per-(block,bin) bases
__global__ __launch_bounds__(256) void scan_c_kernel(
    const int* __restrict__ counts, const int* __restrict__ tstart,
    int* __restrict__ bbase)
{
    int b = blockIdx.x * 256 + threadIdx.x;
    if (b >= NBIN) return;
    int run = tstart[b];
    for (int k = 0; k < NB2; ++k) {
        bbase[(size_t)k * NBIN + b] = run;
        run += counts[(size_t)k * NBIN + b];
    }
}

__global__ __launch_bounds__(256) void bin_scatter_kernel(
    const int* __restrict__ row, const int* __restrict__ col,
    const int* __restrict__ bbase, const int* __restrict__ tstart,
    const int* __restrict__ tend, unsigned* __restrict__ binned)
{
    // block 0 fills alignment pads with sentinels (ws is 0xAA-poisoned!)
    if (blockIdx.x == 0) {
        for (int b = threadIdx.x; b < NBIN; b += 256) {
            for (int p = tend[b]; p < tstart[b + 1]; ++p)
                binned[p] = 0xFFFFFFFFu;
        }
    }
    __shared__ int cur[NBIN];
    const int* myb = bbase + (size_t)blockIdx.x * NBIN;
    for (int i = threadIdx.x; i < NBIN; i += 256) cur[i] = myb[i];
    __syncthreads();
    const int base = blockIdx.x * CHUNK2;
    const int4* r4 = reinterpret_cast<const int4*>(row + base);
    const int4* c4 = reinterpret_cast<const int4*>(col + base);
    for (int i = threadIdx.x; i < CHUNK2 / 4; i += 256) {
        int4 r = r4[i], c = c4[i];
        int rr[4] = {r.x, r.y, r.z, r.w};
        int cc[4] = {c.x, c.y, c.z, c.w};
#pragma unroll
        for (int k = 0; k < 4; ++k) {
            int bin = (rr[k] >> RSH) * NCX + (cc[k] >> CSH);
            int pos = atomicAdd(&cur[bin], 1);
            binned[pos] = ((unsigned)rr[k] << 16) | (unsigned)cc[k];
        }
    }
}

// grid (NR, SC), 512 thr: all per-edge reads from LDS; s2 streamed by tile.
__global__ __launch_bounds__(512) void range_sum_kernel(
    const unsigned* __restrict__ binned, const int* __restrict__ tstart,
    const float* __restrict__ combh, const float* __restrict__ s2h,
    float* __restrict__ partial)
{
    __shared__ float acc[RNODES * H];   // 8 KB (swizzled)
    __shared__ v8h  sh1[RNODES];        // 4 KB
    __shared__ v8h  s2t[CNODES];        // 32 KB
    const int rx = blockIdx.x;
    const int rbase = rx << RSH;
    const v8h* combv = reinterpret_cast<const v8h*>(combh);
    const v8h* s2v   = reinterpret_cast<const v8h*>(s2h);

    for (int i = threadIdx.x; i < RNODES * H; i += 512) acc[i] = 0.f;
    for (int d = threadIdx.x; d < RNODES; d += 512) {
        int n = rbase + d;
        if (n >= NN) n = NN - 1;
        sh1[d] = combv[(size_t)n * 2];
    }

    const uint4* b4 = reinterpret_cast<const uint4*>(binned);
    for (int cx = blockIdx.y; cx < NCX; cx += SC) {
        __syncthreads();                       // protect s2t from prev readers
        const int cb = cx << CSH;
        for (int j = threadIdx.x; j < CNODES; j += 512) {
            int n = cb + j;
            if (n >= NN) n = NN - 1;
            s2t[j] = s2v[n];
        }
        __syncthreads();
        const int bin = rx * NCX + cx;
        const int p0 = tstart[bin] >> 2, p1 = tstart[bin + 1] >> 2;
        for (int i = p0 + threadIdx.x; i < p1; i += 512) {
            uint4 q = b4[i];
            unsigned pk[4] = {q.x, q.y, q.z, q.w};
#pragma unroll
            for (int k = 0; k < 4; ++k) {
                unsigned d = (pk[k] >> 16) - (unsigned)rbase;
                if (d >= (unsigned)RNODES) continue;     // sentinel pad
                unsigned cl = (pk[k] & 0xFFFFu) - (unsigned)cb;
                v8h a = sh1[d];
                v8h b = s2t[cl];
                float* ap = &acc[d << 3];
#pragma unroll
                for (int h = 0; h < H; ++h) {
                    float t = (float)a[h] + (float)b[h];
                    t = fmaxf(t, ALPHA * t);
                    atomicAdd(ap + ((h + d) & 7), __expf(t));   // swizzled banks
                }
            }
        }
    }
    __syncthreads();

    const int cnt = min(RNODES, NN - rbase);
    float* outp = partial + ((size_t)blockIdx.y * NN + rbase) * H;
    for (int j = threadIdx.x; j < cnt * H; j += 512) {
        int d = j >> 3, h = j & 7;
        outp[j] = acc[(d << 3) + ((h + d) & 7)];       // unswizzle
    }
}

// per-node: fold stripe partials, store lnrec = -log(sum+eps) as fp16
__global__ __launch_bounds__(256) void node_final_kernel(
    const float* __restrict__ partial, float* __restrict__ combh)
{
    int n = blockIdx.x * 256 + threadIdx.x;
    if (n >= NN) return;
    const float4* p4 = reinterpret_cast<const float4*>(partial);
    float4 lo = p4[(size_t)n * 2], hi = p4[(size_t)n * 2 + 1];
#pragma unroll
    for (int s = 1; s < SC; ++s) {
        float4 a = p4[(size_t)s * (NN * 2) + n * 2];
        float4 b = p4[(size_t)s * (NN * 2) + n * 2 + 1];
        lo.x += a.x; lo.y += a.y; lo.z += a.z; lo.w += a.w;
        hi.x += b.x; hi.y += b.y; hi.z += b.z; hi.w += b.w;
    }
    float s8[8] = {lo.x, lo.y, lo.z, lo.w, hi.x, hi.y, hi.z, hi.w};
    v8h lnh;
#pragma unroll
    for (int h = 0; h < H; ++h) lnh[h] = (_Float16)(-__logf(s8[h] + EPS));
    reinterpret_cast<v8h*>(combh)[(size_t)n * 2 + 1] = lnh;
}

// eid-order: 4 edges/thread; 2 miss streams (comb line + s2 line);
// coalesced float4 stores per h-plane (WRITE_SIZE = exactly 51.2 MB).
__global__ __launch_bounds__(256) void edge_out_kernel(
    const int* __restrict__ row, const int* __restrict__ col,
    const float* __restrict__ combh, const float* __restrict__ s2h,
    float* __restrict__ out)
{
    int e0 = (blockIdx.x * 256 + threadIdx.x) * 4;
    if (e0 >= NE) return;
    int4 r4 = *reinterpret_cast<const int4*>(row + e0);
    int4 c4 = *reinterpret_cast<const int4*>(col + e0);
    int rr[4] = {r4.x, r4.y, r4.z, r4.w};
    int cc[4] = {c4.x, c4.y, c4.z, c4.w};
    const v8h* combv = reinterpret_cast<const v8h*>(combh);
    const v8h* s2v   = reinterpret_cast<const v8h*>(s2h);

    float res[4][H];
#pragma unroll
    for (int k = 0; k < 4; ++k) {
        v8h a  = combv[(size_t)rr[k] * 2];
        v8h ln = combv[(size_t)rr[k] * 2 + 1];
        v8h b  = s2v[cc[k]];
#pragma unroll
        for (int h = 0; h < H; ++h) {
            float t = (float)a[h] + (float)b[h];
            t = fmaxf(t, ALPHA * t);
            res[k][h] = __expf(t + (float)ln[h]);   // == exp(leaky(t)) / (sum+eps)
        }
    }
#pragma unroll
    for (int h = 0; h < H; ++h) {
        *reinterpret_cast<float4*>(out + (size_t)h * NE + e0) =
            make_float4(res[0][h], res[1][h], res[2][h], res[3][h]);
    }
}

extern "C" void kernel_launch(void* const* d_in, const int* in_sizes, int n_in,
                              void* d_out, int out_size, void* d_ws, size_t ws_size,
                              hipStream_t stream) {
    const float* x   = (const float*)d_in[0];
    const float* aa  = (const float*)d_in[1];
    const int*   row = (const int*)d_in[2];
    const int*   col = (const int*)d_in[3];
    float* out = (float*)d_out;

    // ws (~9.0 MB)
    float* s2h   = (float*)d_ws;                          // NN*4 floats
    float* combh = s2h + (size_t)NN * 4;                  // NN*8 floats
    unsigned* binned = (unsigned*)(combh + (size_t)NN * 8); // NE + 4*NBIN + 64
    int* tstart  = (int*)(binned + NE + 4 * NBIN + 64);   // NBIN+1
    int* tend    = tstart + NBIN + 1;                     // NBIN
    int* gtot    = tend + NBIN;                           // NBIN

    // out-region scratch (fully consumed before edge_out rewrites out)
    float* partial = out;                                 // SC*NN*H floats (6.4M)
    int* counts = (int*)(out + (size_t)SC * NN * H);      // NB2*NBIN (2.5M)
    int* bbase  = counts + (size_t)NB2 * NBIN;            // NB2*NBIN (2.5M)

    node_proj_kernel<<<(NN + 255) / 256, 256, 0, stream>>>(x, aa, combh, s2h);
    bin_count_kernel<<<NB2, 256, 0, stream>>>(row, col, counts);
    scan_a_kernel<<<(NBIN + 255) / 256, 256, 0, stream>>>(counts, gtot);
    scan_b_kernel<<<1, 1024, 0, stream>>>(gtot, tstart, tend);
    scan_c_kernel<<<(NBIN + 255) / 256, 256, 0, stream>>>(counts, tstart, bbase);
    bin_scatter_kernel<<<NB2, 256, 0, stream>>>(row, col, bbase, tstart, tend, binned);
    range_sum_kernel<<<dim3(NR, SC), 512, 0, stream>>>(binned, tstart, combh, s2h, partial);
    node_final_kernel<<<(NN + 255) / 256, 256, 0, stream>>>(partial, combh);
    edge_out_kernel<<<(NE / 4 + 255) / 256, 256, 0, stream>>>(row, col, combh, s2h, out);
}